// Round 1
// baseline (951.937 us; speedup 1.0000x reference)
//
#include <hip/hip_runtime.h>
#include <math.h>

// Problem constants (fixed by the reference setup_inputs)
#define D      64
#define L      4
#define R      5
#define NBASES 2
#define BGRAPH 1024
#define KTOT   (R*D + D)   // 384: stacked [W_0..W_4; root]

// ---------------- counting sort by segment = dst*R + etype ----------------
__global__ void hist_kernel(const int* __restrict__ dst, const int* __restrict__ et,
                            int* __restrict__ hist, int E) {
    int e = blockIdx.x * blockDim.x + threadIdx.x;
    if (e < E) atomicAdd(&hist[dst[e] * R + et[e]], 1);
}

__global__ void scan1(const int* __restrict__ hist, int* __restrict__ offs,
                      int* __restrict__ bsums, int n) {
    __shared__ int tmp[256];
    int i = blockIdx.x * 256 + threadIdx.x;
    int v = (i < n) ? hist[i] : 0;
    tmp[threadIdx.x] = v;
    __syncthreads();
    for (int o = 1; o < 256; o <<= 1) {
        int t = 0;
        if (threadIdx.x >= o) t = tmp[threadIdx.x - o];
        __syncthreads();
        if (threadIdx.x >= o) tmp[threadIdx.x] += t;
        __syncthreads();
    }
    if (i < n) offs[i] = tmp[threadIdx.x] - v;   // exclusive
    if (threadIdx.x == 255) bsums[blockIdx.x] = tmp[255];
}

__global__ void scan2(int* __restrict__ bsums, int nb) {
    __shared__ int tmp[1024];
    int v = (threadIdx.x < nb) ? bsums[threadIdx.x] : 0;
    tmp[threadIdx.x] = v;
    __syncthreads();
    for (int o = 1; o < 1024; o <<= 1) {
        int t = 0;
        if (threadIdx.x >= o) t = tmp[threadIdx.x - o];
        __syncthreads();
        if (threadIdx.x >= o) tmp[threadIdx.x] += t;
        __syncthreads();
    }
    if (threadIdx.x < nb) bsums[threadIdx.x] = tmp[threadIdx.x] - v;  // exclusive
}

__global__ void scan3(int* __restrict__ offs, const int* __restrict__ bsums,
                      int n, int total) {
    int i = blockIdx.x * 256 + threadIdx.x;
    if (i < n) offs[i] += bsums[blockIdx.x];
    if (i == 0) offs[n] = total;
}

__global__ void scatter_kernel(const int* __restrict__ src, const int* __restrict__ dst,
                               const int* __restrict__ et, const int* __restrict__ offs,
                               int* __restrict__ cursor, int* __restrict__ ssrc, int E) {
    int e = blockIdx.x * blockDim.x + threadIdx.x;
    if (e < E) {
        int seg = dst[e] * R + et[e];
        int pos = offs[seg] + atomicAdd(&cursor[seg], 1);
        ssrc[pos] = src[e];
    }
}

// --------------- build stacked weights M[l][k][d], k in [0,384) ---------------
// k < 320: W_r rows (r = k>>6, input dim i = k&63); k >= 320: root rows.
__global__ void buildM(const float* __restrict__ basis, const float* __restrict__ comp,
                       const float* __restrict__ root, float* __restrict__ M) {
    int idx = blockIdx.x * blockDim.x + threadIdx.x;
    if (idx >= L * KTOT * D) return;
    int d = idx & 63;
    int k = (idx >> 6) % KTOT;
    int l = idx / (KTOT * D);
    float v;
    if (k < R * D) {
        int r = k >> 6, i = k & 63;
        float c0 = comp[(l * R + r) * NBASES + 0];
        float c1 = comp[(l * R + r) * NBASES + 1];
        v = c0 * basis[((l * NBASES + 0) * D + i) * D + d]
          + c1 * basis[((l * NBASES + 1) * D + i) * D + d];
    } else {
        int i = k - R * D;
        v = root[(l * D + i) * D + d];
    }
    M[idx] = v;
}

// --------------- per-(node,relation) CSR mean aggregation ---------------
// one wave per segment; lane = feature dim; coalesced 256B gathers of h[src]
__global__ void aggregate(const int* __restrict__ offs, const int* __restrict__ ssrc,
                          const float* __restrict__ h, float* __restrict__ acc, int NS) {
    int s = blockIdx.x * (blockDim.x >> 6) + (threadIdx.x >> 6);
    int lane = threadIdx.x & 63;
    if (s >= NS) return;
    int b = offs[s], e = offs[s + 1];
    float sum = 0.f;
    for (int i = b; i < e; ++i) {
        sum += h[(size_t)ssrc[i] * D + lane];
    }
    int cnt = e - b;
    acc[(size_t)s * D + lane] = (cnt > 0) ? sum * (1.0f / (float)cnt) : 0.f;
}

// --------------- dense transform: h_out = tanh([acc | h] @ M + bias) ---------------
#define NPW 4   // nodes per wave
#define TW  8   // waves per block (512 threads)
__global__ void transform(const float* __restrict__ acc, const float* __restrict__ h,
                          const float* __restrict__ M, const float* __restrict__ bias,
                          float* __restrict__ hout, float* __restrict__ g,
                          int l, int N) {
    __shared__ float Mc[D * 64];   // one 64-row chunk of M: 16 KB
    int wid = threadIdx.x >> 6, lane = threadIdx.x & 63;
    int vbase = (blockIdx.x * TW + wid) * NPW;
    float s[NPW];
    float bl = bias[l * D + lane];
    #pragma unroll
    for (int j = 0; j < NPW; ++j) s[j] = bl;

    for (int c = 0; c < 6; ++c) {   // 5 chunks of acc (320) + 1 chunk of h (64)
        __syncthreads();
        const float4* msrc = (const float4*)(M + ((size_t)l * KTOT + c * 64) * 64);
        for (int t = threadIdx.x; t < (D * 64) / 4; t += TW * 64)
            ((float4*)Mc)[t] = msrc[t];
        __syncthreads();

        float a[NPW];
        #pragma unroll
        for (int j = 0; j < NPW; ++j) {
            int v = vbase + j;
            if (v < N)
                a[j] = (c < 5) ? acc[(size_t)v * (R * D) + c * 64 + lane]
                               : h[(size_t)v * D + lane];
            else
                a[j] = 0.f;
        }
        #pragma unroll
        for (int k = 0; k < 64; ++k) {
            float m = Mc[k * 64 + lane];
            #pragma unroll
            for (int j = 0; j < NPW; ++j) {
                float av = __uint_as_float(
                    __builtin_amdgcn_readlane(__float_as_uint(a[j]), k));
                s[j] = fmaf(av, m, s[j]);
            }
        }
    }

    #pragma unroll
    for (int j = 0; j < NPW; ++j) {
        int v = vbase + j;
        if (v < N) {
            float t = tanhf(s[j]);
            hout[(size_t)v * D + lane] = t;
            // users are rows [0,B), movies rows [B,2B) by construction of x
            if (v < BGRAPH)
                g[(size_t)v * (2 * L * D) + l * D + lane] = t;
            else if (v < 2 * BGRAPH)
                g[(size_t)(v - BGRAPH) * (2 * L * D) + L * D + l * D + lane] = t;
        }
    }
}

// --------------- final MLP: out = relu(g@w1+b1)@w2 + b2 ---------------
__global__ void mlp(const float* __restrict__ g, const float* __restrict__ w1,
                    const float* __restrict__ b1, const float* __restrict__ w2,
                    const float* __restrict__ b2, float* __restrict__ out) {
    int row = blockIdx.x;
    int t = threadIdx.x;   // 0..127
    const float* gr = g + (size_t)row * (2 * L * D);
    float s = b1[t];
    for (int k = 0; k < 2 * L * D; ++k)
        s = fmaf(gr[k], w1[k * 128 + t], s);
    float hv = fmaxf(s, 0.f) * w2[t];
    __shared__ float red[128];
    red[t] = hv;
    __syncthreads();
    for (int o = 64; o > 0; o >>= 1) {
        if (t < o) red[t] += red[t + o];
        __syncthreads();
    }
    if (t == 0) out[row] = red[0] + b2[0];
}

extern "C" void kernel_launch(void* const* d_in, const int* in_sizes, int n_in,
                              void* d_out, int out_size, void* d_ws, size_t ws_size,
                              hipStream_t stream) {
    const float* x     = (const float*)d_in[0];
    const float* basis = (const float*)d_in[1];
    const float* comp  = (const float*)d_in[2];
    const float* root  = (const float*)d_in[3];
    const float* bias  = (const float*)d_in[4];
    const float* w1    = (const float*)d_in[5];
    const float* b1    = (const float*)d_in[6];
    const float* w2    = (const float*)d_in[7];
    const float* b2    = (const float*)d_in[8];
    const int*   src   = (const int*)d_in[9];
    const int*   dst   = (const int*)d_in[10];
    const int*   et    = (const int*)d_in[11];
    float* out = (float*)d_out;

    const int N  = in_sizes[0] / D;   // 50000
    const int E  = in_sizes[9];       // 1200000
    const int NS = N * R;             // 250000 segments

    // workspace carve-out (~99 MB)
    char* p = (char*)d_ws;
    auto alloc = [&](size_t bytes) -> char* {
        char* q = p;
        p += (bytes + 255) & ~(size_t)255;
        return q;
    };
    int*   offs  = (int*)alloc((size_t)(NS + 1) * 4);
    int*   hist  = (int*)alloc((size_t)NS * 4);
    int*   bsums = (int*)alloc(1024 * 4);
    int*   ssrc  = (int*)alloc((size_t)E * 4);
    float* acc   = (float*)alloc((size_t)NS * D * 4);
    float* h0    = (float*)alloc((size_t)N * D * 4);
    float* h1    = (float*)alloc((size_t)N * D * 4);
    float* gbuf  = (float*)alloc((size_t)BGRAPH * 2 * L * D * 4);
    float* M     = (float*)alloc((size_t)L * KTOT * D * 4);

    // edge sort (counts depend only on dst/etype -> once per launch)
    hipMemsetAsync(hist, 0, (size_t)NS * 4, stream);
    hist_kernel<<<(E + 255) / 256, 256, 0, stream>>>(dst, et, hist, E);
    int nb = (NS + 255) / 256;   // 977 <= 1024
    scan1<<<nb, 256, 0, stream>>>(hist, offs, bsums, NS);
    scan2<<<1, 1024, 0, stream>>>(bsums, nb);
    scan3<<<nb, 256, 0, stream>>>(offs, bsums, NS, E);
    hipMemsetAsync(hist, 0, (size_t)NS * 4, stream);
    scatter_kernel<<<(E + 255) / 256, 256, 0, stream>>>(src, dst, et, offs, hist, ssrc, E);

    buildM<<<(L * KTOT * D + 255) / 256, 256, 0, stream>>>(basis, comp, root, M);

    const float* hcur = x;
    float* hb[2] = { h0, h1 };
    for (int l = 0; l < L; ++l) {
        aggregate<<<(NS + 3) / 4, 256, 0, stream>>>(offs, ssrc, hcur, acc, NS);
        int ngrp = (N + TW * NPW - 1) / (TW * NPW);
        transform<<<ngrp, TW * 64, 0, stream>>>(acc, hcur, M, bias, hb[l & 1], gbuf, l, N);
        hcur = hb[l & 1];
    }
    mlp<<<BGRAPH, 128, 0, stream>>>(gbuf, w1, b1, w2, b2, out);
}

// Round 2
// 815.731 us; speedup vs baseline: 1.1670x; 1.1670x over previous
//
#include <hip/hip_runtime.h>
#include <math.h>

// Problem constants (fixed by the reference setup_inputs)
#define D      64
#define L      4
#define R      5
#define NBASES 2
#define BGRAPH 1024
#define KTOT   (R*D + D)   // 384: stacked [W_0..W_4; root]

// ---------------- counting sort by segment = dst*R + etype ----------------
__global__ void hist_kernel(const int* __restrict__ dst, const int* __restrict__ et,
                            int* __restrict__ hist, int E) {
    int e = blockIdx.x * blockDim.x + threadIdx.x;
    if (e < E) atomicAdd(&hist[dst[e] * R + et[e]], 1);
}

__global__ void scan1(const int* __restrict__ hist, int* __restrict__ offs,
                      int* __restrict__ bsums, int n) {
    __shared__ int tmp[256];
    int i = blockIdx.x * 256 + threadIdx.x;
    int v = (i < n) ? hist[i] : 0;
    tmp[threadIdx.x] = v;
    __syncthreads();
    for (int o = 1; o < 256; o <<= 1) {
        int t = 0;
        if (threadIdx.x >= o) t = tmp[threadIdx.x - o];
        __syncthreads();
        if (threadIdx.x >= o) tmp[threadIdx.x] += t;
        __syncthreads();
    }
    if (i < n) offs[i] = tmp[threadIdx.x] - v;   // exclusive
    if (threadIdx.x == 255) bsums[blockIdx.x] = tmp[255];
}

__global__ void scan2(int* __restrict__ bsums, int nb) {
    __shared__ int tmp[1024];
    int v = (threadIdx.x < nb) ? bsums[threadIdx.x] : 0;
    tmp[threadIdx.x] = v;
    __syncthreads();
    for (int o = 1; o < 1024; o <<= 1) {
        int t = 0;
        if (threadIdx.x >= o) t = tmp[threadIdx.x - o];
        __syncthreads();
        if (threadIdx.x >= o) tmp[threadIdx.x] += t;
        __syncthreads();
    }
    if (threadIdx.x < nb) bsums[threadIdx.x] = tmp[threadIdx.x] - v;  // exclusive
}

__global__ void scan3(int* __restrict__ offs, const int* __restrict__ bsums,
                      int n, int total) {
    int i = blockIdx.x * 256 + threadIdx.x;
    if (i < n) offs[i] += bsums[blockIdx.x];
    if (i == 0) offs[n] = total;
}

__global__ void scatter_kernel(const int* __restrict__ src, const int* __restrict__ dst,
                               const int* __restrict__ et, const int* __restrict__ offs,
                               int* __restrict__ cursor, int* __restrict__ ssrc, int E) {
    int e = blockIdx.x * blockDim.x + threadIdx.x;
    if (e < E) {
        int seg = dst[e] * R + et[e];
        int pos = offs[seg] + atomicAdd(&cursor[seg], 1);
        ssrc[pos] = src[e];
    }
}

// --------------- build stacked weights M[l][k][d], k in [0,384) ---------------
// k < 320: W_r rows (r = k>>6, input dim i = k&63); k >= 320: root rows.
__global__ void buildM(const float* __restrict__ basis, const float* __restrict__ comp,
                       const float* __restrict__ root, float* __restrict__ M) {
    int idx = blockIdx.x * blockDim.x + threadIdx.x;
    if (idx >= L * KTOT * D) return;
    int d = idx & 63;
    int k = (idx >> 6) % KTOT;
    int l = idx / (KTOT * D);
    float v;
    if (k < R * D) {
        int r = k >> 6, i = k & 63;
        float c0 = comp[(l * R + r) * NBASES + 0];
        float c1 = comp[(l * R + r) * NBASES + 1];
        v = c0 * basis[((l * NBASES + 0) * D + i) * D + d]
          + c1 * basis[((l * NBASES + 1) * D + i) * D + d];
    } else {
        int i = k - R * D;
        v = root[(l * D + i) * D + d];
    }
    M[idx] = v;
}

// --------------- fused layer: gather-mean + dense transform + tanh ---------------
// One wave handles NPW nodes. Per node, all 5 relation segments are contiguous
// in ssrc (seg = v*5+r), so a single edge loop with 8-deep batched gathers keeps
// 8 loads in flight; relation routing is via wave-uniform branches.
#define NPW 4   // nodes per wave
#define TW  8   // waves per block (512 threads)
__global__ void rgcn_fused(const int* __restrict__ offs, const int* __restrict__ ssrc,
                           const float* __restrict__ h, const float* __restrict__ M,
                           const float* __restrict__ bias,
                           float* __restrict__ hout, float* __restrict__ g,
                           int l, int N) {
    __shared__ float Mc[D * 64];   // one 64-row chunk of M: 16 KB
    int wid = threadIdx.x >> 6, lane = threadIdx.x & 63;
    int vbase = (blockIdx.x * TW + wid) * NPW;

    float mean[NPW][R];
    float hv[NPW];

    // ---- gather phase ----
    #pragma unroll
    for (int j = 0; j < NPW; ++j) {
        int v = vbase + j;
        float s0 = 0.f, s1 = 0.f, s2 = 0.f, s3 = 0.f, s4 = 0.f;
        int c0 = 1, c1 = 1, c2 = 1, c3 = 1, c4 = 1;
        if (v < N) {                           // wave-uniform branch
            hv[j] = h[(size_t)v * D + lane];
            int o0 = offs[v * R + 0], o1 = offs[v * R + 1], o2 = offs[v * R + 2];
            int o3 = offs[v * R + 3], o4 = offs[v * R + 4], o5 = offs[v * R + 5];
            for (int i = o0; i < o5; i += 8) {
                int idx[8];
                float val[8];
                #pragma unroll
                for (int t = 0; t < 8; ++t) {
                    int gi = i + t;
                    idx[t] = ssrc[gi < o5 ? gi : (o5 - 1)];   // clamped, unconditional
                }
                #pragma unroll
                for (int t = 0; t < 8; ++t)
                    val[t] = h[(size_t)idx[t] * D + lane];     // 8 gathers in flight
                #pragma unroll
                for (int t = 0; t < 8; ++t) {
                    int gi = i + t;
                    float vv = (gi < o5) ? val[t] : 0.f;
                    if (gi < o1)      s0 += vv;   // uniform: all lanes share v, o*
                    else if (gi < o2) s1 += vv;
                    else if (gi < o3) s2 += vv;
                    else if (gi < o4) s3 += vv;
                    else              s4 += vv;   // gi>=o5 adds 0
                }
            }
            c0 = max(o1 - o0, 1); c1 = max(o2 - o1, 1); c2 = max(o3 - o2, 1);
            c3 = max(o4 - o3, 1); c4 = max(o5 - o4, 1);
        } else {
            hv[j] = 0.f;
        }
        mean[j][0] = s0 / (float)c0;
        mean[j][1] = s1 / (float)c1;
        mean[j][2] = s2 / (float)c2;
        mean[j][3] = s3 / (float)c3;
        mean[j][4] = s4 / (float)c4;
    }

    // ---- transform phase: s = [mean_0..mean_4 | h] @ M + bias ----
    float s[NPW];
    float bl = bias[l * D + lane];
    #pragma unroll
    for (int j = 0; j < NPW; ++j) s[j] = bl;

    #pragma unroll
    for (int c = 0; c < 6; ++c) {
        __syncthreads();
        const float4* msrc = (const float4*)(M + ((size_t)l * KTOT + c * 64) * 64);
        for (int t = threadIdx.x; t < (D * 64) / 4; t += TW * 64)
            ((float4*)Mc)[t] = msrc[t];
        __syncthreads();
        #pragma unroll
        for (int k = 0; k < 64; ++k) {
            float m = Mc[k * 64 + lane];
            #pragma unroll
            for (int j = 0; j < NPW; ++j) {
                float aj = (c < 5) ? mean[j][c] : hv[j];
                float av = __uint_as_float(
                    __builtin_amdgcn_readlane(__float_as_uint(aj), k));
                s[j] = fmaf(av, m, s[j]);
            }
        }
    }

    #pragma unroll
    for (int j = 0; j < NPW; ++j) {
        int v = vbase + j;
        if (v < N) {
            float t = tanhf(s[j]);
            hout[(size_t)v * D + lane] = t;
            // users are rows [0,B), movies rows [B,2B) by construction of x
            if (v < BGRAPH)
                g[(size_t)v * (2 * L * D) + l * D + lane] = t;
            else if (v < 2 * BGRAPH)
                g[(size_t)(v - BGRAPH) * (2 * L * D) + L * D + l * D + lane] = t;
        }
    }
}

// --------------- final MLP: out = relu(g@w1+b1)@w2 + b2 ---------------
__global__ void mlp(const float* __restrict__ g, const float* __restrict__ w1,
                    const float* __restrict__ b1, const float* __restrict__ w2,
                    const float* __restrict__ b2, float* __restrict__ out) {
    int row = blockIdx.x;
    int t = threadIdx.x;   // 0..127
    const float* gr = g + (size_t)row * (2 * L * D);
    float s = b1[t];
    for (int k = 0; k < 2 * L * D; ++k)
        s = fmaf(gr[k], w1[k * 128 + t], s);
    float hv = fmaxf(s, 0.f) * w2[t];
    __shared__ float red[128];
    red[t] = hv;
    __syncthreads();
    for (int o = 64; o > 0; o >>= 1) {
        if (t < o) red[t] += red[t + o];
        __syncthreads();
    }
    if (t == 0) out[row] = red[0] + b2[0];
}

extern "C" void kernel_launch(void* const* d_in, const int* in_sizes, int n_in,
                              void* d_out, int out_size, void* d_ws, size_t ws_size,
                              hipStream_t stream) {
    const float* x     = (const float*)d_in[0];
    const float* basis = (const float*)d_in[1];
    const float* comp  = (const float*)d_in[2];
    const float* root  = (const float*)d_in[3];
    const float* bias  = (const float*)d_in[4];
    const float* w1    = (const float*)d_in[5];
    const float* b1    = (const float*)d_in[6];
    const float* w2    = (const float*)d_in[7];
    const float* b2    = (const float*)d_in[8];
    const int*   src   = (const int*)d_in[9];
    const int*   dst   = (const int*)d_in[10];
    const int*   et    = (const int*)d_in[11];
    float* out = (float*)d_out;

    const int N  = in_sizes[0] / D;   // 50000
    const int E  = in_sizes[9];       // 1200000
    const int NS = N * R;             // 250000 segments

    // workspace carve-out
    char* p = (char*)d_ws;
    auto alloc = [&](size_t bytes) -> char* {
        char* q = p;
        p += (bytes + 255) & ~(size_t)255;
        return q;
    };
    int*   offs  = (int*)alloc((size_t)(NS + 1) * 4);
    int*   hist  = (int*)alloc((size_t)NS * 4);
    int*   bsums = (int*)alloc(1024 * 4);
    int*   ssrc  = (int*)alloc((size_t)E * 4);
    float* h0    = (float*)alloc((size_t)N * D * 4);
    float* h1    = (float*)alloc((size_t)N * D * 4);
    float* gbuf  = (float*)alloc((size_t)BGRAPH * 2 * L * D * 4);
    float* M     = (float*)alloc((size_t)L * KTOT * D * 4);

    // edge sort (counts depend only on dst/etype -> once per launch)
    hipMemsetAsync(hist, 0, (size_t)NS * 4, stream);
    hist_kernel<<<(E + 255) / 256, 256, 0, stream>>>(dst, et, hist, E);
    int nb = (NS + 255) / 256;   // 977 <= 1024
    scan1<<<nb, 256, 0, stream>>>(hist, offs, bsums, NS);
    scan2<<<1, 1024, 0, stream>>>(bsums, nb);
    scan3<<<nb, 256, 0, stream>>>(offs, bsums, NS, E);
    hipMemsetAsync(hist, 0, (size_t)NS * 4, stream);
    scatter_kernel<<<(E + 255) / 256, 256, 0, stream>>>(src, dst, et, offs, hist, ssrc, E);

    buildM<<<(L * KTOT * D + 255) / 256, 256, 0, stream>>>(basis, comp, root, M);

    const float* hcur = x;
    float* hb[2] = { h0, h1 };
    int ngrp = (N + TW * NPW - 1) / (TW * NPW);
    for (int l = 0; l < L; ++l) {
        rgcn_fused<<<ngrp, TW * 64, 0, stream>>>(offs, ssrc, hcur, M, bias,
                                                 hb[l & 1], gbuf, l, N);
        hcur = hb[l & 1];
    }
    mlp<<<BGRAPH, 128, 0, stream>>>(gbuf, w1, b1, w2, b2, out);
}

// Round 3
// 668.017 us; speedup vs baseline: 1.4250x; 1.2211x over previous
//
#include <hip/hip_runtime.h>
#include <math.h>

// Problem constants (fixed by the reference setup_inputs)
#define D      64
#define L      4
#define R      5
#define BGRAPH 1024
#define KT     (3 * D)     // 192: stacked [B0; B1; root]
#define NPW    4           // nodes per wave
#define BT     512         // threads per fused block
#define BW     (BT / 64)   // 8 waves per block

// ---------------- histogram: per-node (sort key) and per-(node,rel) (counts) ----------------
__global__ void hist_kernel(const int* __restrict__ dst, const int* __restrict__ et,
                            int* __restrict__ cntNR, int* __restrict__ histN, int E) {
    int e = blockIdx.x * blockDim.x + threadIdx.x;
    if (e < E) {
        int d = dst[e];
        atomicAdd(&cntNR[d * R + et[e]], 1);
        atomicAdd(&histN[d], 1);
    }
}

__global__ void scan1(const int* __restrict__ hist, int* __restrict__ offs,
                      int* __restrict__ bsums, int n) {
    __shared__ int tmp[256];
    int i = blockIdx.x * 256 + threadIdx.x;
    int v = (i < n) ? hist[i] : 0;
    tmp[threadIdx.x] = v;
    __syncthreads();
    for (int o = 1; o < 256; o <<= 1) {
        int t = 0;
        if (threadIdx.x >= o) t = tmp[threadIdx.x - o];
        __syncthreads();
        if (threadIdx.x >= o) tmp[threadIdx.x] += t;
        __syncthreads();
    }
    if (i < n) offs[i] = tmp[threadIdx.x] - v;   // exclusive
    if (threadIdx.x == 255) bsums[blockIdx.x] = tmp[255];
}

__global__ void scan2(int* __restrict__ bsums, int nb) {
    __shared__ int tmp[1024];
    int v = (threadIdx.x < nb) ? bsums[threadIdx.x] : 0;
    tmp[threadIdx.x] = v;
    __syncthreads();
    for (int o = 1; o < 1024; o <<= 1) {
        int t = 0;
        if (threadIdx.x >= o) t = tmp[threadIdx.x - o];
        __syncthreads();
        if (threadIdx.x >= o) tmp[threadIdx.x] += t;
        __syncthreads();
    }
    if (threadIdx.x < nb) bsums[threadIdx.x] = tmp[threadIdx.x] - v;  // exclusive
}

__global__ void scan3(int* __restrict__ offs, const int* __restrict__ bsums,
                      int n, int total) {
    int i = blockIdx.x * 256 + threadIdx.x;
    if (i < n) offs[i] += bsums[blockIdx.x];
    if (i == 0) offs[n] = total;
}

// ---------------- scatter: sort edges by dst; remember seg = dst*R + et ----------------
__global__ void scatter_kernel(const int* __restrict__ src, const int* __restrict__ dst,
                               const int* __restrict__ et, const int* __restrict__ offs,
                               int* __restrict__ cursor, int* __restrict__ ssrc,
                               int* __restrict__ sseg, int E) {
    int e = blockIdx.x * blockDim.x + threadIdx.x;
    if (e < E) {
        int d = dst[e];
        int pos = offs[d] + atomicAdd(&cursor[d], 1);
        ssrc[pos] = src[e];
        sseg[pos] = d * R + et[e];
    }
}

// ---------------- per-edge, per-layer weights: (comp[l,et,b] / cnt[dst,et]) ----------------
__global__ void wgt_kernel(const int* __restrict__ sseg, const int* __restrict__ cntNR,
                           const float* __restrict__ comp, float2* __restrict__ wgt, int E) {
    int e = blockIdx.x * 256 + threadIdx.x;
    if (e >= E) return;
    int seg = sseg[e];
    int c = cntNR[seg];
    int et = seg % R;
    float inv = 1.0f / (float)c;
    #pragma unroll
    for (int l = 0; l < L; ++l) {
        float c0 = comp[(l * R + et) * 2 + 0] * inv;
        float c1 = comp[(l * R + et) * 2 + 1] * inv;
        wgt[(size_t)l * E + e] = make_float2(c0, c1);
    }
}

// ---------------- stacked weights M[l][k][d]: rows [B0(64); B1(64); root(64)] ----------------
__global__ void buildM(const float* __restrict__ basis, const float* __restrict__ root,
                       float* __restrict__ M) {
    int idx = blockIdx.x * blockDim.x + threadIdx.x;
    if (idx >= L * KT * D) return;
    int d = idx & 63;
    int k = (idx >> 6) % KT;
    int l = idx / (KT * D);
    float v;
    if (k < 2 * D) {
        int b = k >> 6, i = k & 63;
        v = basis[(((size_t)l * 2 + b) * D + i) * D + d];
    } else {
        int i = k - 2 * D;
        v = root[((size_t)l * D + i) * D + d];
    }
    M[idx] = v;
}

// ---------------- fused layer: weighted gather + [z0|z1|h] @ M + tanh ----------------
__global__ __launch_bounds__(BT, 6)
void rgcn_fused(const int* __restrict__ offs, const int* __restrict__ ssrc,
                const float2* __restrict__ wgt,        // this layer's per-edge weights
                const float* __restrict__ h,
                const float* __restrict__ M,           // this layer's [192][64]
                const float* __restrict__ bias,        // this layer's [64]
                float* __restrict__ hout, float* __restrict__ g,
                int l, int N) {
    __shared__ float Mc[KT * D];   // 48 KB, loaded once per block
    for (int t = threadIdx.x; t < (KT * D) / 4; t += BT)
        ((float4*)Mc)[t] = ((const float4*)M)[t];
    __syncthreads();

    int wid = threadIdx.x >> 6, lane = threadIdx.x & 63;
    float bl = bias[lane];
    int gw = blockIdx.x * BW + wid;
    int nw = gridDim.x * BW;

    for (int vbase = gw * NPW; vbase < N; vbase += nw * NPW) {
        float z0[NPW], z1[NPW], hv[NPW];

        // ---- gather: routing-free weighted sum over the node's whole edge range ----
        #pragma unroll
        for (int j = 0; j < NPW; ++j) {
            int v = vbase + j;
            float s0 = 0.f, s1 = 0.f;
            if (v < N) {                          // wave-uniform
                hv[j] = h[(size_t)v * D + lane];
                int b = offs[v], e2 = offs[v + 1];
                for (int i = b; i < e2; i += 8) {
                    int idx[8]; float2 w[8];
                    #pragma unroll
                    for (int t = 0; t < 8; ++t) {
                        int gi = i + t;
                        int gic = gi < e2 ? gi : e2 - 1;   // clamped, unconditional
                        idx[t] = ssrc[gic];
                        w[t] = wgt[gic];
                    }
                    float val[8];
                    #pragma unroll
                    for (int t = 0; t < 8; ++t)
                        val[t] = h[(size_t)idx[t] * D + lane];  // 8 gathers in flight
                    #pragma unroll
                    for (int t = 0; t < 8; ++t) {
                        bool ok = (i + t) < e2;
                        s0 = fmaf(ok ? w[t].x : 0.f, val[t], s0);
                        s1 = fmaf(ok ? w[t].y : 0.f, val[t], s1);
                    }
                }
            } else {
                hv[j] = 0.f;
            }
            z0[j] = s0; z1[j] = s1;
        }

        // ---- transform: s = z0@B0 + z1@B1 + h@root + bias (K = 192) ----
        float s[NPW];
        #pragma unroll
        for (int j = 0; j < NPW; ++j) s[j] = bl;

        #pragma unroll 8
        for (int k = 0; k < D; ++k) {            // k uniform -> readlane from SGPR
            float m0 = Mc[k * D + lane];
            float m1 = Mc[(D + k) * D + lane];
            float m2 = Mc[(2 * D + k) * D + lane];
            #pragma unroll
            for (int j = 0; j < NPW; ++j) {
                s[j] = fmaf(__uint_as_float(__builtin_amdgcn_readlane(__float_as_uint(z0[j]), k)), m0, s[j]);
                s[j] = fmaf(__uint_as_float(__builtin_amdgcn_readlane(__float_as_uint(z1[j]), k)), m1, s[j]);
                s[j] = fmaf(__uint_as_float(__builtin_amdgcn_readlane(__float_as_uint(hv[j]), k)), m2, s[j]);
            }
        }

        // ---- activation + stores ----
        #pragma unroll
        for (int j = 0; j < NPW; ++j) {
            int v = vbase + j;
            if (v < N) {
                float t = tanhf(s[j]);
                hout[(size_t)v * D + lane] = t;
                if (v < BGRAPH)
                    g[(size_t)v * (2 * L * D) + l * D + lane] = t;
                else if (v < 2 * BGRAPH)
                    g[(size_t)(v - BGRAPH) * (2 * L * D) + L * D + l * D + lane] = t;
            }
        }
    }
}

// --------------- final MLP: out = relu(g@w1+b1)@w2 + b2 ---------------
__global__ void mlp(const float* __restrict__ g, const float* __restrict__ w1,
                    const float* __restrict__ b1, const float* __restrict__ w2,
                    const float* __restrict__ b2, float* __restrict__ out) {
    int row = blockIdx.x;
    int t = threadIdx.x;   // 0..127
    const float* gr = g + (size_t)row * (2 * L * D);
    float s = b1[t];
    for (int k = 0; k < 2 * L * D; ++k)
        s = fmaf(gr[k], w1[k * 128 + t], s);
    float hv = fmaxf(s, 0.f) * w2[t];
    __shared__ float red[128];
    red[t] = hv;
    __syncthreads();
    for (int o = 64; o > 0; o >>= 1) {
        if (t < o) red[t] += red[t + o];
        __syncthreads();
    }
    if (t == 0) out[row] = red[0] + b2[0];
}

extern "C" void kernel_launch(void* const* d_in, const int* in_sizes, int n_in,
                              void* d_out, int out_size, void* d_ws, size_t ws_size,
                              hipStream_t stream) {
    const float* x     = (const float*)d_in[0];
    const float* basis = (const float*)d_in[1];
    const float* comp  = (const float*)d_in[2];
    const float* root  = (const float*)d_in[3];
    const float* bias  = (const float*)d_in[4];
    const float* w1    = (const float*)d_in[5];
    const float* b1    = (const float*)d_in[6];
    const float* w2    = (const float*)d_in[7];
    const float* b2    = (const float*)d_in[8];
    const int*   src   = (const int*)d_in[9];
    const int*   dst   = (const int*)d_in[10];
    const int*   et    = (const int*)d_in[11];
    float* out = (float*)d_out;

    const int N = in_sizes[0] / D;   // 50000
    const int E = in_sizes[9];       // 1200000

    // workspace carve-out (~78 MB)
    char* p = (char*)d_ws;
    auto alloc = [&](size_t bytes) -> char* {
        char* q = p;
        p += (bytes + 255) & ~(size_t)255;
        return q;
    };
    int*    offsN = (int*)alloc((size_t)(N + 1) * 4);
    int*    histN = (int*)alloc((size_t)N * 4);
    int*    cntNR = (int*)alloc((size_t)N * R * 4);
    int*    bsums = (int*)alloc(1024 * 4);
    int*    ssrc  = (int*)alloc((size_t)E * 4);
    int*    sseg  = (int*)alloc((size_t)E * 4);
    float2* wgt   = (float2*)alloc((size_t)L * E * 8);
    float*  h0    = (float*)alloc((size_t)N * D * 4);
    float*  h1    = (float*)alloc((size_t)N * D * 4);
    float*  gbuf  = (float*)alloc((size_t)BGRAPH * 2 * L * D * 4);
    float*  M     = (float*)alloc((size_t)L * KT * D * 4);

    // ---- sort phase (dst-only sort; per-(dst,rel) counts feed edge weights) ----
    hipMemsetAsync(cntNR, 0, (size_t)N * R * 4, stream);
    hipMemsetAsync(histN, 0, (size_t)N * 4, stream);
    hist_kernel<<<(E + 255) / 256, 256, 0, stream>>>(dst, et, cntNR, histN, E);
    int nb = (N + 255) / 256;   // 196 <= 1024
    scan1<<<nb, 256, 0, stream>>>(histN, offsN, bsums, N);
    scan2<<<1, 1024, 0, stream>>>(bsums, nb);
    scan3<<<nb, 256, 0, stream>>>(offsN, bsums, N, E);
    hipMemsetAsync(histN, 0, (size_t)N * 4, stream);
    scatter_kernel<<<(E + 255) / 256, 256, 0, stream>>>(src, dst, et, offsN, histN, ssrc, sseg, E);
    wgt_kernel<<<(E + 255) / 256, 256, 0, stream>>>(sseg, cntNR, comp, wgt, E);

    buildM<<<(L * KT * D + 255) / 256, 256, 0, stream>>>(basis, root, M);

    // ---- layers ----
    const float* hcur = x;
    float* hb[2] = { h0, h1 };
    for (int l = 0; l < L; ++l) {
        rgcn_fused<<<768, BT, 0, stream>>>(offsN, ssrc, wgt + (size_t)l * E, hcur,
                                           M + (size_t)l * KT * D, bias + (size_t)l * D,
                                           hb[l & 1], gbuf, l, N);
        hcur = hb[l & 1];
    }
    mlp<<<BGRAPH, 128, 0, stream>>>(gbuf, w1, b1, w2, b2, out);
}

// Round 4
// 544.580 us; speedup vs baseline: 1.7480x; 1.2267x over previous
//
#include <hip/hip_runtime.h>
#include <hip/hip_fp16.h>
#include <math.h>

// Problem constants (fixed by the reference setup_inputs)
#define D      64
#define L      4
#define R      5
#define BGRAPH 1024

typedef __attribute__((ext_vector_type(8))) short short8;
typedef __attribute__((ext_vector_type(4))) float f32x4;

__device__ __forceinline__ ushort f2bf(float f) {          // RTN-even fp32->bf16
    unsigned u = __float_as_uint(f);
    return (ushort)((u + 0x7FFFu + ((u >> 16) & 1u)) >> 16);
}
__device__ __forceinline__ float bf2f(ushort h) {
    return __uint_as_float(((unsigned)h) << 16);
}

// ---------------- histogram: per-node (sort key) and per-(node,rel) counts ----------------
__global__ void hist_kernel(const int* __restrict__ dst, const int* __restrict__ et,
                            int* __restrict__ cntNR, int* __restrict__ histN, int E) {
    int e = blockIdx.x * blockDim.x + threadIdx.x;
    if (e < E) {
        int d = dst[e];
        atomicAdd(&cntNR[d * R + et[e]], 1);
        atomicAdd(&histN[d], 1);
    }
}

__global__ void scan1(const int* __restrict__ hist, int* __restrict__ offs,
                      int* __restrict__ bsums, int n) {
    __shared__ int tmp[256];
    int i = blockIdx.x * 256 + threadIdx.x;
    int v = (i < n) ? hist[i] : 0;
    tmp[threadIdx.x] = v;
    __syncthreads();
    for (int o = 1; o < 256; o <<= 1) {
        int t = 0;
        if (threadIdx.x >= o) t = tmp[threadIdx.x - o];
        __syncthreads();
        if (threadIdx.x >= o) tmp[threadIdx.x] += t;
        __syncthreads();
    }
    if (i < n) offs[i] = tmp[threadIdx.x] - v;   // exclusive
    if (threadIdx.x == 255) bsums[blockIdx.x] = tmp[255];
}

__global__ void scan2(int* __restrict__ bsums, int nb) {
    __shared__ int tmp[1024];
    int v = (threadIdx.x < nb) ? bsums[threadIdx.x] : 0;
    tmp[threadIdx.x] = v;
    __syncthreads();
    for (int o = 1; o < 1024; o <<= 1) {
        int t = 0;
        if (threadIdx.x >= o) t = tmp[threadIdx.x - o];
        __syncthreads();
        if (threadIdx.x >= o) tmp[threadIdx.x] += t;
        __syncthreads();
    }
    if (threadIdx.x < nb) bsums[threadIdx.x] = tmp[threadIdx.x] - v;  // exclusive
}

__global__ void scan3(int* __restrict__ offs, const int* __restrict__ bsums,
                      int n, int total) {
    int i = blockIdx.x * 256 + threadIdx.x;
    if (i < n) offs[i] += bsums[blockIdx.x];
    if (i == 0) offs[n] = total;
}

// ---- scatter: sort edges by dst, pack meta = (src | et<<20, bits(1/cnt(dst,et))) ----
__global__ void scatter_meta(const int* __restrict__ src, const int* __restrict__ dst,
                             const int* __restrict__ et, const int* __restrict__ offs,
                             int* __restrict__ cursor, const int* __restrict__ cntNR,
                             int2* __restrict__ meta, int E) {
    int e = blockIdx.x * blockDim.x + threadIdx.x;
    if (e < E) {
        int d = dst[e], r = et[e];
        int pos = offs[d] + atomicAdd(&cursor[d], 1);
        float invc = 1.0f / (float)cntNR[d * R + r];
        meta[pos] = make_int2(src[e] | (r << 20), __float_as_int(invc));
    }
}

// ---- M in split-bf16 B-fragment layout: [l][cg][kt][lane][8], k-rows = [B0|B1|root] ----
__global__ void buildMfrag(const float* __restrict__ basis, const float* __restrict__ root,
                           ushort* __restrict__ Mhi, ushort* __restrict__ Mlo) {
    int t = blockIdx.x * 256 + threadIdx.x;
    if (t >= L * 4 * 6 * 64 * 8) return;
    int j = t & 7;
    int lane = (t >> 3) & 63;
    int rem = t >> 9;              // ((l*4+cg)*6+kt)
    int kt = rem % 6;
    int lcg = rem / 6;
    int cg = lcg & 3, l = lcg >> 2;
    int k = kt * 32 + (lane >> 4) * 8 + j;
    int col = cg * 16 + (lane & 15);
    float val;
    if (k < 64)       val = basis[(((size_t)l * 2 + 0) * D + k) * D + col];
    else if (k < 128) val = basis[(((size_t)l * 2 + 1) * D + (k - 64)) * D + col];
    else              val = root[((size_t)l * D + (k - 128)) * D + col];
    ushort hi = f2bf(val);
    Mhi[t] = hi;
    Mlo[t] = f2bf(val - bf2f(hi));
}

// ---- x -> Z0 h-cols (fp32) + hf (fp16 gather copy) ----
__global__ void copyX(const float* __restrict__ x, float* __restrict__ Z0,
                      __half* __restrict__ hf, int NE) {
    int i = blockIdx.x * 256 + threadIdx.x;
    if (i >= NE) return;
    float v = x[i];
    Z0[(size_t)(i >> 6) * 192 + 128 + (i & 63)] = v;
    hf[i] = __float2half(v);
}

// ---- gather: z_b[v] = sum_e (comp[l,et,b]/cnt) * h[src]; writes Z cols [0,128) ----
__global__ void gather_k(const int* __restrict__ offs, const int2* __restrict__ meta,
                         const __half* __restrict__ hf, const float* __restrict__ comp_l,
                         float* __restrict__ Z, int N) {
    int wid = threadIdx.x >> 6, lane = threadIdx.x & 63;
    int vbase = (blockIdx.x * 4 + wid) * 4;
    // comp coefficients as wave-uniform (SGPR) values
    float c00 = __uint_as_float(__builtin_amdgcn_readfirstlane(__float_as_uint(comp_l[0])));
    float c01 = __uint_as_float(__builtin_amdgcn_readfirstlane(__float_as_uint(comp_l[1])));
    float c10 = __uint_as_float(__builtin_amdgcn_readfirstlane(__float_as_uint(comp_l[2])));
    float c11 = __uint_as_float(__builtin_amdgcn_readfirstlane(__float_as_uint(comp_l[3])));
    float c20 = __uint_as_float(__builtin_amdgcn_readfirstlane(__float_as_uint(comp_l[4])));
    float c21 = __uint_as_float(__builtin_amdgcn_readfirstlane(__float_as_uint(comp_l[5])));
    float c30 = __uint_as_float(__builtin_amdgcn_readfirstlane(__float_as_uint(comp_l[6])));
    float c31 = __uint_as_float(__builtin_amdgcn_readfirstlane(__float_as_uint(comp_l[7])));
    float c40 = __uint_as_float(__builtin_amdgcn_readfirstlane(__float_as_uint(comp_l[8])));
    float c41 = __uint_as_float(__builtin_amdgcn_readfirstlane(__float_as_uint(comp_l[9])));

    for (int j = 0; j < 4; ++j) {
        int v = vbase + j;
        if (v >= N) break;
        int b  = __builtin_amdgcn_readfirstlane(offs[v]);
        int e2 = __builtin_amdgcn_readfirstlane(offs[v + 1]);
        float s0 = 0.f, s1 = 0.f;
        for (int base = b; base < e2; base += 64) {
            int gi = base + lane;
            int mx = 0, my = 0;
            if (gi < e2) { int2 mp = meta[gi]; mx = mp.x; my = mp.y; }  // lane t holds edge base+t
            int rem = e2 - base; if (rem > 64) rem = 64;
            int ng = (rem + 7) >> 3;                     // 8-edge groups; pads have w=0
            for (int grp = 0; grp < ng; ++grp) {
                #pragma unroll
                for (int t8 = 0; t8 < 8; ++t8) {
                    int t = grp * 8 + t8;
                    int pk   = __builtin_amdgcn_readlane(mx, t);      // SGPR-uniform
                    float ic = __uint_as_float(__builtin_amdgcn_readlane(my, t));
                    int idx = pk & 0xFFFFF;
                    int et  = ((unsigned)pk) >> 20;
                    float c0 = et == 0 ? c00 : et == 1 ? c10 : et == 2 ? c20 : et == 3 ? c30 : c40;
                    float c1 = et == 0 ? c01 : et == 1 ? c11 : et == 2 ? c21 : et == 3 ? c31 : c41;
                    float hv = __half2float(hf[idx * D + lane]);      // 128B coalesced gather
                    s0 = fmaf(c0 * ic, hv, s0);
                    s1 = fmaf(c1 * ic, hv, s1);
                }
            }
        }
        Z[(size_t)v * 192 + lane]      = s0;
        Z[(size_t)v * 192 + 64 + lane] = s1;
    }
}

// ---- transform: tanh([z0|z1|h] @ M + bias) via split-bf16 MFMA (exact to ~2^-17) ----
__global__ __launch_bounds__(256)
void transform_k(const float* __restrict__ Z, const ushort* __restrict__ Mhi_l,
                 const ushort* __restrict__ Mlo_l, const float* __restrict__ bias_l,
                 float* __restrict__ Znext, __half* __restrict__ hfo,
                 float* __restrict__ g, int l, int N) {
    int wid = threadIdx.x >> 6, lane = threadIdx.x & 63;
    int tile = blockIdx.x * 4 + wid;
    if (tile * 16 >= N) return;
    int m = lane & 15, lg = lane >> 4;

    // A-frags straight from Z: lane holds row (tile*16+m), k = lg*8 .. +7 per k-tile
    const float* arow = Z + (size_t)(tile * 16 + m) * 192 + lg * 8;
    short8 ahi[6], alo[6];
    #pragma unroll
    for (int kt = 0; kt < 6; ++kt) {
        f32x4 x0 = *(const f32x4*)(arow + kt * 32);
        f32x4 x1 = *(const f32x4*)(arow + kt * 32 + 4);
        union { short8 v; ushort u[8]; } H, Lw;
        #pragma unroll
        for (int q = 0; q < 8; ++q) {
            float f = q < 4 ? x0[q] : x1[q - 4];
            ushort hi = f2bf(f);
            H.u[q] = hi;
            Lw.u[q] = f2bf(f - bf2f(hi));
        }
        ahi[kt] = H.v;
        alo[kt] = Lw.v;
    }

    #pragma unroll
    for (int cg = 0; cg < 4; ++cg) {
        int col = cg * 16 + m;
        float bv = bias_l[col];
        f32x4 acc = { bv, bv, bv, bv };
        #pragma unroll
        for (int kt = 0; kt < 6; ++kt) {
            size_t boff = ((size_t)(cg * 6 + kt) * 64 + lane) * 8;
            short8 bhi = *(const short8*)(Mhi_l + boff);
            short8 blo = *(const short8*)(Mlo_l + boff);
            acc = __builtin_amdgcn_mfma_f32_16x16x32_bf16(ahi[kt], bhi, acc, 0, 0, 0);
            acc = __builtin_amdgcn_mfma_f32_16x16x32_bf16(ahi[kt], blo, acc, 0, 0, 0);
            acc = __builtin_amdgcn_mfma_f32_16x16x32_bf16(alo[kt], bhi, acc, 0, 0, 0);
        }
        int rowbase = tile * 16 + lg * 4;      // C/D: col=lane&15, row=(lane>>4)*4+reg
        #pragma unroll
        for (int r = 0; r < 4; ++r) {
            int node = rowbase + r;
            float tv = tanhf(acc[r]);
            Znext[(size_t)node * 192 + 128 + col] = tv;
            hfo[node * D + col] = __float2half(tv);
            if (node < BGRAPH)
                g[(size_t)node * (2 * L * D) + l * D + col] = tv;
            else if (node < 2 * BGRAPH)
                g[(size_t)(node - BGRAPH) * (2 * L * D) + L * D + l * D + col] = tv;
        }
    }
}

// ---- final MLP: 4 rows per block; w1 streamed once per block ----
__global__ void mlp4(const float* __restrict__ g, const float* __restrict__ w1,
                     const float* __restrict__ b1, const float* __restrict__ w2,
                     const float* __restrict__ b2, float* __restrict__ out) {
    __shared__ float gl[4][512];
    __shared__ float red[2][4][128];
    int tid = threadIdx.x;
    int rowbase = blockIdx.x * 4;
    for (int i = tid; i < 4 * 512; i += 256)
        gl[i >> 9][i & 511] = g[(size_t)rowbase * 512 + i];
    __syncthreads();
    int t = tid & 127, kh = tid >> 7;
    float s0 = 0.f, s1 = 0.f, s2 = 0.f, s3 = 0.f;
    int k0 = kh * 256;
    #pragma unroll 4
    for (int k = k0; k < k0 + 256; ++k) {
        float wv = w1[k * 128 + t];
        s0 = fmaf(gl[0][k], wv, s0);
        s1 = fmaf(gl[1][k], wv, s1);
        s2 = fmaf(gl[2][k], wv, s2);
        s3 = fmaf(gl[3][k], wv, s3);
    }
    red[kh][0][t] = s0; red[kh][1][t] = s1; red[kh][2][t] = s2; red[kh][3][t] = s3;
    __syncthreads();
    if (kh == 0) {
        #pragma unroll
        for (int r = 0; r < 4; ++r)
            gl[r][t] = fmaxf(red[0][r][t] + red[1][r][t] + b1[t], 0.f) * w2[t];
    }
    __syncthreads();
    int w = tid >> 6, lane = tid & 63;
    float val = gl[w][lane] + gl[w][lane + 64];
    #pragma unroll
    for (int o = 32; o > 0; o >>= 1) val += __shfl_down(val, o);
    if (lane == 0) out[rowbase + w] = val + b2[0];
}

extern "C" void kernel_launch(void* const* d_in, const int* in_sizes, int n_in,
                              void* d_out, int out_size, void* d_ws, size_t ws_size,
                              hipStream_t stream) {
    const float* x     = (const float*)d_in[0];
    const float* basis = (const float*)d_in[1];
    const float* comp  = (const float*)d_in[2];
    const float* root  = (const float*)d_in[3];
    const float* bias  = (const float*)d_in[4];
    const float* w1    = (const float*)d_in[5];
    const float* b1    = (const float*)d_in[6];
    const float* w2    = (const float*)d_in[7];
    const float* b2    = (const float*)d_in[8];
    const int*   src   = (const int*)d_in[9];
    const int*   dst   = (const int*)d_in[10];
    const int*   et    = (const int*)d_in[11];
    float* out = (float*)d_out;

    const int N = in_sizes[0] / D;   // 50000
    const int E = in_sizes[9];       // 1200000

    // workspace carve-out (~96 MB)
    char* p = (char*)d_ws;
    auto alloc = [&](size_t bytes) -> char* {
        char* q = p;
        p += (bytes + 255) & ~(size_t)255;
        return q;
    };
    int*    offsN = (int*)alloc((size_t)(N + 1) * 4);
    int*    histN = (int*)alloc((size_t)N * 4);
    int*    cntNR = (int*)alloc((size_t)N * R * 4);
    int*    bsums = (int*)alloc(1024 * 4);
    int2*   meta  = (int2*)alloc((size_t)E * 8);
    float*  Z0    = (float*)alloc((size_t)N * 192 * 4);
    float*  Z1    = (float*)alloc((size_t)N * 192 * 4);
    __half* hf    = (__half*)alloc((size_t)N * D * 2);
    float*  gbuf  = (float*)alloc((size_t)BGRAPH * 2 * L * D * 4);
    ushort* Mhi   = (ushort*)alloc((size_t)L * 4 * 6 * 64 * 8 * 2);
    ushort* Mlo   = (ushort*)alloc((size_t)L * 4 * 6 * 64 * 8 * 2);

    // ---- sort phase ----
    hipMemsetAsync(cntNR, 0, (size_t)N * R * 4, stream);
    hipMemsetAsync(histN, 0, (size_t)N * 4, stream);
    hist_kernel<<<(E + 255) / 256, 256, 0, stream>>>(dst, et, cntNR, histN, E);
    int nb = (N + 255) / 256;   // 196 <= 1024
    scan1<<<nb, 256, 0, stream>>>(histN, offsN, bsums, N);
    scan2<<<1, 1024, 0, stream>>>(bsums, nb);
    scan3<<<nb, 256, 0, stream>>>(offsN, bsums, N, E);
    hipMemsetAsync(histN, 0, (size_t)N * 4, stream);
    scatter_meta<<<(E + 255) / 256, 256, 0, stream>>>(src, dst, et, offsN, histN, cntNR, meta, E);

    buildMfrag<<<(L * 4 * 6 * 64 * 8 + 255) / 256, 256, 0, stream>>>(basis, root, Mhi, Mlo);
    copyX<<<(N * D + 255) / 256, 256, 0, stream>>>(x, Z0, hf, N * D);

    // ---- layers ----
    float* Zb[2] = { Z0, Z1 };
    int ggrid = (N + 15) / 16;           // 3125
    int tgrid = ((N + 15) / 16 + 3) / 4; // 782
    for (int l = 0; l < L; ++l) {
        gather_k<<<ggrid, 256, 0, stream>>>(offsN, meta, hf, comp + (size_t)l * R * 2,
                                            Zb[l & 1], N);
        transform_k<<<tgrid, 256, 0, stream>>>(Zb[l & 1],
                                               Mhi + (size_t)l * 4 * 6 * 64 * 8,
                                               Mlo + (size_t)l * 4 * 6 * 64 * 8,
                                               bias + (size_t)l * D,
                                               Zb[(l + 1) & 1], hf, gbuf, l, N);
    }
    mlp4<<<BGRAPH / 4, 256, 0, stream>>>(gbuf, w1, b1, w2, b2, out);
}

// Round 5
// 425.145 us; speedup vs baseline: 2.2391x; 1.2809x over previous
//
#include <hip/hip_runtime.h>
#include <hip/hip_fp16.h>
#include <math.h>

// Problem constants (fixed by the reference setup_inputs)
#define D      64
#define L      4
#define R      5
#define BGRAPH 1024

typedef __attribute__((ext_vector_type(8))) short short8;
typedef __attribute__((ext_vector_type(4))) float f32x4;

__device__ __forceinline__ ushort f2bf(float f) {          // RTN-even fp32->bf16
    unsigned u = __float_as_uint(f);
    return (ushort)((u + 0x7FFFu + ((u >> 16) & 1u)) >> 16);
}
__device__ __forceinline__ float bf2f(ushort h) {
    return __uint_as_float(((unsigned)h) << 16);
}

// ---- histogram: ONE u64 atomic per edge; 12-bit field per relation ----
__global__ void hist64(const int* __restrict__ dst, const int* __restrict__ et,
                       unsigned long long* __restrict__ cnt64, int E) {
    int e = blockIdx.x * blockDim.x + threadIdx.x;
    if (e < E) atomicAdd(&cnt64[dst[e]], 1ull << (12 * et[e]));
}

// ---- per-node totals derived atomic-free ----
__global__ void histN_k(const unsigned long long* __restrict__ cnt64,
                        int* __restrict__ histN, int N) {
    int d = blockIdx.x * 256 + threadIdx.x;
    if (d < N) {
        unsigned long long c = cnt64[d];
        int s = 0;
        #pragma unroll
        for (int r = 0; r < R; ++r) s += (int)((c >> (12 * r)) & 0xFFFull);
        histN[d] = s;
    }
}

__global__ void scan1(const int* __restrict__ hist, int* __restrict__ offs,
                      int* __restrict__ bsums, int n) {
    __shared__ int tmp[256];
    int i = blockIdx.x * 256 + threadIdx.x;
    int v = (i < n) ? hist[i] : 0;
    tmp[threadIdx.x] = v;
    __syncthreads();
    for (int o = 1; o < 256; o <<= 1) {
        int t = 0;
        if (threadIdx.x >= o) t = tmp[threadIdx.x - o];
        __syncthreads();
        if (threadIdx.x >= o) tmp[threadIdx.x] += t;
        __syncthreads();
    }
    if (i < n) offs[i] = tmp[threadIdx.x] - v;   // exclusive
    if (threadIdx.x == 255) bsums[blockIdx.x] = tmp[255];
}

__global__ void scan2(int* __restrict__ bsums, int nb) {
    __shared__ int tmp[1024];
    int v = (threadIdx.x < nb) ? bsums[threadIdx.x] : 0;
    tmp[threadIdx.x] = v;
    __syncthreads();
    for (int o = 1; o < 1024; o <<= 1) {
        int t = 0;
        if (threadIdx.x >= o) t = tmp[threadIdx.x - o];
        __syncthreads();
        if (threadIdx.x >= o) tmp[threadIdx.x] += t;
        __syncthreads();
    }
    if (threadIdx.x < nb) bsums[threadIdx.x] = tmp[threadIdx.x] - v;  // exclusive
}

__global__ void scan3(int* __restrict__ offs, const int* __restrict__ bsums,
                      int n, int total) {
    int i = blockIdx.x * 256 + threadIdx.x;
    if (i < n) offs[i] += bsums[blockIdx.x];
    if (i == 0) offs[n] = total;
}

// ---- scatter: 4B permutation only (1 cursor atomic per edge) ----
__global__ void scatter_perm(const int* __restrict__ dst, const int* __restrict__ offs,
                             int* __restrict__ cursor, int* __restrict__ perm, int E) {
    int e = blockIdx.x * blockDim.x + threadIdx.x;
    if (e < E) {
        int d = dst[e];
        int pos = offs[d] + atomicAdd(&cursor[d], 1);
        perm[pos] = e;
    }
}

// ---- linear expansion: sorted src + premultiplied per-layer (c0/cnt, c1/cnt) ----
__global__ void expand_wgt(const int* __restrict__ perm, const int* __restrict__ src,
                           const int* __restrict__ dst, const int* __restrict__ et,
                           const unsigned long long* __restrict__ cnt64,
                           const float* __restrict__ comp,
                           int* __restrict__ ssrc, float2* __restrict__ wgtL, int E) {
    int pos = blockIdx.x * 256 + threadIdx.x;
    if (pos >= E) return;
    int e = perm[pos];
    int r = et[e], d = dst[e];
    float invc = 1.0f / (float)((cnt64[d] >> (12 * r)) & 0xFFFull);
    ssrc[pos] = src[e];
    #pragma unroll
    for (int l = 0; l < L; ++l) {
        float2 w;
        w.x = comp[(l * R + r) * 2 + 0] * invc;
        w.y = comp[(l * R + r) * 2 + 1] * invc;
        wgtL[(size_t)l * E + pos] = w;
    }
}

// ---- M in split-bf16 B-fragment layout: [l][cg][kt][lane][8], k-rows = [B0|B1|root] ----
__global__ void buildMfrag(const float* __restrict__ basis, const float* __restrict__ root,
                           ushort* __restrict__ Mhi, ushort* __restrict__ Mlo) {
    int t = blockIdx.x * 256 + threadIdx.x;
    if (t >= L * 4 * 6 * 64 * 8) return;
    int j = t & 7;
    int lane = (t >> 3) & 63;
    int rem = t >> 9;              // ((l*4+cg)*6+kt)
    int kt = rem % 6;
    int lcg = rem / 6;
    int cg = lcg & 3, l = lcg >> 2;
    int k = kt * 32 + (lane >> 4) * 8 + j;
    int col = cg * 16 + (lane & 15);
    float val;
    if (k < 64)       val = basis[(((size_t)l * 2 + 0) * D + k) * D + col];
    else if (k < 128) val = basis[(((size_t)l * 2 + 1) * D + (k - 64)) * D + col];
    else              val = root[((size_t)l * D + (k - 128)) * D + col];
    ushort hi = f2bf(val);
    Mhi[t] = hi;
    Mlo[t] = f2bf(val - bf2f(hi));
}

// ---- x -> Z h-cols (fp32) + hf (fp16 gather copy) ----
__global__ void copyX(const float* __restrict__ x, float* __restrict__ Z,
                      __half* __restrict__ hf, int NE) {
    int i = blockIdx.x * 256 + threadIdx.x;
    if (i >= NE) return;
    float v = x[i];
    Z[(size_t)(i >> 6) * 192 + 128 + (i & 63)] = v;
    hf[i] = __float2half(v);
}

// ---- gather: z_b[v] = sum_e w_e,b * h[src_e]; uniform scalar loads, 2 fmac/edge ----
__global__ __launch_bounds__(256)
void gather_k(const int* __restrict__ offs, const int* __restrict__ ssrc,
              const float2* __restrict__ wgt, const __half* __restrict__ hf,
              float* __restrict__ Z, int N) {
    int wid = threadIdx.x >> 6, lane = threadIdx.x & 63;
    int vbase = (blockIdx.x * 4 + wid) * 4;
    for (int j = 0; j < 4; ++j) {
        int v = vbase + j;
        if (v >= N) return;                    // wave-uniform
        int b  = __builtin_amdgcn_readfirstlane(offs[v]);
        int e2 = __builtin_amdgcn_readfirstlane(offs[v + 1]);
        float s0a = 0.f, s0b = 0.f, s1a = 0.f, s1b = 0.f;
        int i = b;
        #pragma unroll 4
        for (; i + 1 < e2; i += 2) {           // pair-unrolled: 8 gathers in flight
            int sA = ssrc[i], sB = ssrc[i + 1];          // uniform -> s_load
            float2 wA = wgt[i], wB = wgt[i + 1];         // uniform -> s_load
            float hA = __half2float(hf[(size_t)sA * D + lane]);
            float hB = __half2float(hf[(size_t)sB * D + lane]);
            s0a = fmaf(wA.x, hA, s0a); s1a = fmaf(wA.y, hA, s1a);
            s0b = fmaf(wB.x, hB, s0b); s1b = fmaf(wB.y, hB, s1b);
        }
        if (i < e2) {
            int sA = ssrc[i];
            float2 wA = wgt[i];
            float hA = __half2float(hf[(size_t)sA * D + lane]);
            s0a = fmaf(wA.x, hA, s0a); s1a = fmaf(wA.y, hA, s1a);
        }
        Z[(size_t)v * 192 + lane]      = s0a + s0b;
        Z[(size_t)v * 192 + 64 + lane] = s1a + s1b;
    }
}

// ---- transform: tanh([z0|z1|h] @ M + bias) via split-bf16 MFMA; IN-PLACE on Z ----
// (each wave reads only the 16 rows it later writes -> no cross-thread hazard)
__global__ __launch_bounds__(256)
void transform_k(float* __restrict__ Z, const ushort* __restrict__ Mhi_l,
                 const ushort* __restrict__ Mlo_l, const float* __restrict__ bias_l,
                 __half* __restrict__ hfo, float* __restrict__ g, int l, int N) {
    int wid = threadIdx.x >> 6, lane = threadIdx.x & 63;
    int tile = blockIdx.x * 4 + wid;
    if (tile * 16 >= N) return;
    int m = lane & 15, lg = lane >> 4;

    // A-frags straight from Z: lane holds row (tile*16+m), k = lg*8 .. +7 per k-tile
    const float* arow = Z + (size_t)(tile * 16 + m) * 192 + lg * 8;
    short8 ahi[6], alo[6];
    #pragma unroll
    for (int kt = 0; kt < 6; ++kt) {
        f32x4 x0 = *(const f32x4*)(arow + kt * 32);
        f32x4 x1 = *(const f32x4*)(arow + kt * 32 + 4);
        union { short8 v; ushort u[8]; } H, Lw;
        #pragma unroll
        for (int q = 0; q < 8; ++q) {
            float f = q < 4 ? x0[q] : x1[q - 4];
            ushort hi = f2bf(f);
            H.u[q] = hi;
            Lw.u[q] = f2bf(f - bf2f(hi));
        }
        ahi[kt] = H.v;
        alo[kt] = Lw.v;
    }

    #pragma unroll
    for (int cg = 0; cg < 4; ++cg) {
        int col = cg * 16 + m;
        float bv = bias_l[col];
        f32x4 acc = { bv, bv, bv, bv };
        #pragma unroll
        for (int kt = 0; kt < 6; ++kt) {
            size_t boff = ((size_t)(cg * 6 + kt) * 64 + lane) * 8;
            short8 bhi = *(const short8*)(Mhi_l + boff);
            short8 blo = *(const short8*)(Mlo_l + boff);
            acc = __builtin_amdgcn_mfma_f32_16x16x32_bf16(ahi[kt], bhi, acc, 0, 0, 0);
            acc = __builtin_amdgcn_mfma_f32_16x16x32_bf16(ahi[kt], blo, acc, 0, 0, 0);
            acc = __builtin_amdgcn_mfma_f32_16x16x32_bf16(alo[kt], bhi, acc, 0, 0, 0);
        }
        int rowbase = tile * 16 + lg * 4;      // C/D: col=lane&15, row=(lane>>4)*4+reg
        #pragma unroll
        for (int r = 0; r < 4; ++r) {
            int node = rowbase + r;
            float tv = tanhf(acc[r]);
            Z[(size_t)node * 192 + 128 + col] = tv;
            hfo[node * D + col] = __float2half(tv);
            if (node < BGRAPH)
                g[(size_t)node * (2 * L * D) + l * D + col] = tv;
            else if (node < 2 * BGRAPH)
                g[(size_t)(node - BGRAPH) * (2 * L * D) + L * D + l * D + col] = tv;
        }
    }
}

// ---- final MLP: 4 rows per block; w1 streamed once per block ----
__global__ void mlp4(const float* __restrict__ g, const float* __restrict__ w1,
                     const float* __restrict__ b1, const float* __restrict__ w2,
                     const float* __restrict__ b2, float* __restrict__ out) {
    __shared__ float gl[4][512];
    __shared__ float red[2][4][128];
    int tid = threadIdx.x;
    int rowbase = blockIdx.x * 4;
    for (int i = tid; i < 4 * 512; i += 256)
        gl[i >> 9][i & 511] = g[(size_t)rowbase * 512 + i];
    __syncthreads();
    int t = tid & 127, kh = tid >> 7;
    float s0 = 0.f, s1 = 0.f, s2 = 0.f, s3 = 0.f;
    int k0 = kh * 256;
    #pragma unroll 4
    for (int k = k0; k < k0 + 256; ++k) {
        float wv = w1[k * 128 + t];
        s0 = fmaf(gl[0][k], wv, s0);
        s1 = fmaf(gl[1][k], wv, s1);
        s2 = fmaf(gl[2][k], wv, s2);
        s3 = fmaf(gl[3][k], wv, s3);
    }
    red[kh][0][t] = s0; red[kh][1][t] = s1; red[kh][2][t] = s2; red[kh][3][t] = s3;
    __syncthreads();
    if (kh == 0) {
        #pragma unroll
        for (int r = 0; r < 4; ++r)
            gl[r][t] = fmaxf(red[0][r][t] + red[1][r][t] + b1[t], 0.f) * w2[t];
    }
    __syncthreads();
    int w = tid >> 6, lane = tid & 63;
    float val = gl[w][lane] + gl[w][lane + 64];
    #pragma unroll
    for (int o = 32; o > 0; o >>= 1) val += __shfl_down(val, o);
    if (lane == 0) out[rowbase + w] = val + b2[0];
}

extern "C" void kernel_launch(void* const* d_in, const int* in_sizes, int n_in,
                              void* d_out, int out_size, void* d_ws, size_t ws_size,
                              hipStream_t stream) {
    const float* x     = (const float*)d_in[0];
    const float* basis = (const float*)d_in[1];
    const float* comp  = (const float*)d_in[2];
    const float* root  = (const float*)d_in[3];
    const float* bias  = (const float*)d_in[4];
    const float* w1    = (const float*)d_in[5];
    const float* b1    = (const float*)d_in[6];
    const float* w2    = (const float*)d_in[7];
    const float* b2    = (const float*)d_in[8];
    const int*   src   = (const int*)d_in[9];
    const int*   dst   = (const int*)d_in[10];
    const int*   et    = (const int*)d_in[11];
    float* out = (float*)d_out;

    const int N = in_sizes[0] / D;   // 50000
    const int E = in_sizes[9];       // 1200000

    // workspace carve-out (~99 MB)
    char* p = (char*)d_ws;
    auto alloc = [&](size_t bytes) -> char* {
        char* q = p;
        p += (bytes + 255) & ~(size_t)255;
        return q;
    };
    int*    offsN  = (int*)alloc((size_t)(N + 1) * 4);
    int*    histN  = (int*)alloc((size_t)N * 4);
    int*    cursor = (int*)alloc((size_t)N * 4);
    unsigned long long* cnt64 = (unsigned long long*)alloc((size_t)N * 8);
    int*    bsums  = (int*)alloc(1024 * 4);
    int*    perm   = (int*)alloc((size_t)E * 4);
    int*    ssrc   = (int*)alloc((size_t)E * 4);
    float2* wgtL   = (float2*)alloc((size_t)L * E * 8);
    float*  Z      = (float*)alloc((size_t)N * 192 * 4);
    __half* hf     = (__half*)alloc((size_t)N * D * 2);
    float*  gbuf   = (float*)alloc((size_t)BGRAPH * 2 * L * D * 4);
    ushort* Mhi    = (ushort*)alloc((size_t)L * 4 * 6 * 64 * 8 * 2);
    ushort* Mlo    = (ushort*)alloc((size_t)L * 4 * 6 * 64 * 8 * 2);

    // ---- sort phase: 1 u64 atomic (hist) + 1 u32 atomic (cursor) per edge ----
    hipMemsetAsync(cnt64, 0, (size_t)N * 8, stream);
    hipMemsetAsync(cursor, 0, (size_t)N * 4, stream);
    hist64<<<(E + 255) / 256, 256, 0, stream>>>(dst, et, cnt64, E);
    histN_k<<<(N + 255) / 256, 256, 0, stream>>>(cnt64, histN, N);
    int nb = (N + 255) / 256;   // 196 <= 1024
    scan1<<<nb, 256, 0, stream>>>(histN, offsN, bsums, N);
    scan2<<<1, 1024, 0, stream>>>(bsums, nb);
    scan3<<<nb, 256, 0, stream>>>(offsN, bsums, N, E);
    scatter_perm<<<(E + 255) / 256, 256, 0, stream>>>(dst, offsN, cursor, perm, E);
    expand_wgt<<<(E + 255) / 256, 256, 0, stream>>>(perm, src, dst, et, cnt64, comp,
                                                    ssrc, wgtL, E);

    buildMfrag<<<(L * 4 * 6 * 64 * 8 + 255) / 256, 256, 0, stream>>>(basis, root, Mhi, Mlo);
    copyX<<<(N * D + 255) / 256, 256, 0, stream>>>(x, Z, hf, N * D);

    // ---- layers ----
    int ggrid = (N + 15) / 16;           // 3125
    int tgrid = ((N + 15) / 16 + 3) / 4; // 782
    for (int l = 0; l < L; ++l) {
        gather_k<<<ggrid, 256, 0, stream>>>(offsN, ssrc, wgtL + (size_t)l * E, hf, Z, N);
        transform_k<<<tgrid, 256, 0, stream>>>(Z,
                                               Mhi + (size_t)l * 4 * 6 * 64 * 8,
                                               Mlo + (size_t)l * 4 * 6 * 64 * 8,
                                               bias + (size_t)l * D,
                                               hf, gbuf, l, N);
    }
    mlp4<<<BGRAPH / 4, 256, 0, stream>>>(gbuf, w1, b1, w2, b2, out);
}